// Round 13
// baseline (184.312 us; speedup 1.0000x reference)
//
#include <hip/hip_runtime.h>
#include <hip/hip_bf16.h>
#include <cstdint>
#include <cstddef>

// ---------------- problem constants ----------------
constexpr int Bn   = 8;
constexpr int Hn   = 64;
constexpr int Wn   = 64;
constexpr int Cn   = 256;
constexpr int OUTC = 1024;
constexpr int HPAD = 66;   // 64 + 2 halo
constexpr int WPAD = 66;
#define EPS 1e-5f

typedef __attribute__((ext_vector_type(4))) float f32x4;
typedef __bf16 bf16x8 __attribute__((ext_vector_type(8)));

// ---------------- helpers ----------------
__device__ __forceinline__ void gload_lds16(const void* g, void* l) {
    __builtin_amdgcn_global_load_lds(
        (__attribute__((address_space(1))) void*)g,
        (__attribute__((address_space(3))) void*)l,
        16, 0, 0);
}

// ---------------- K0: conv_w [3][3][256][1024] f32 -> wT [9][1024][256] bf16 ----------------
__global__ __launch_bounds__(256) void k0_transpose_w(const float* __restrict__ conv_w,
                                                      __hip_bfloat16* __restrict__ wT) {
    __shared__ float tile[64][65];
    const int tap = blockIdx.x;        // 0..8
    const int ct  = blockIdx.y;        // c-tile 0..3  (64 ch)
    const int ot  = blockIdx.z;        // o-tile 0..15 (64 out)
    const int t   = threadIdx.x;
    const int lo  = t & 63;
    const int cq  = t >> 6;            // 0..3

#pragma unroll
    for (int k = 0; k < 16; ++k) {
        int ci = k * 4 + cq;
        tile[lo][ci] = conv_w[((size_t)(tap * Cn + ct * 64 + ci)) * OUTC + ot * 64 + lo];
    }
    __syncthreads();
#pragma unroll
    for (int k = 0; k < 16; ++k) {
        int oo = k * 4 + cq;
        wT[((size_t)(tap * OUTC + ot * 64 + oo)) * Cn + ct * 64 + lo] =
            __float2bfloat16(tile[oo][lo]);
    }
}

// ---------------- K1: per-(b,h) sums over w (1024 thr: 4 w-slices x 256 ch) ----------------
__global__ __launch_bounds__(1024) void k1_stats_partial(const float* __restrict__ x,
                                                         float* __restrict__ ps,
                                                         float* __restrict__ pq) {
    __shared__ float sb[2][4][256];
    const int bh = blockIdx.x;          // b*64 + h
    const int tid = threadIdx.x;
    const int c = tid & 255;
    const int s = tid >> 8;             // 0..3
    const float* row = x + (size_t)bh * Wn * Cn + (size_t)s * 16 * Cn + c;
    float sm = 0.f, q = 0.f;
#pragma unroll
    for (int w = 0; w < 16; ++w) {
        float v = row[(size_t)w * Cn];
        sm += v; q += v * v;
    }
    sb[0][s][c] = sm; sb[1][s][c] = q;
    __syncthreads();
    if (s == 0) {
        float S = 0.f, Q = 0.f;
#pragma unroll
        for (int k = 0; k < 4; ++k) { S += sb[0][k][c]; Q += sb[1][k][c]; }
        ps[bh * Cn + c] = S;
        pq[bh * Cn + c] = Q;
    }
}

// ---------------- K2: reduce over h, produce scale/shift (1024 thr) ----------------
__global__ __launch_bounds__(1024) void k2_stats_final(const float* __restrict__ ps,
                                                       const float* __restrict__ pq,
                                                       float* __restrict__ scale,
                                                       float* __restrict__ shift) {
    __shared__ float sb[2][4][256];
    const int b = blockIdx.x;
    const int tid = threadIdx.x;
    const int c = tid & 255;
    const int qd = tid >> 8;            // 0..3, each sums 16 h
    float S = 0.f, Q = 0.f;
#pragma unroll 4
    for (int i = 0; i < 16; ++i) {
        int h = qd * 16 + i;
        S += ps[(b * Hn + h) * Cn + c];
        Q += pq[(b * Hn + h) * Cn + c];
    }
    sb[0][qd][c] = S; sb[1][qd][c] = Q;
    __syncthreads();
    if (qd == 0) {
        float s2 = 0.f, q2 = 0.f;
#pragma unroll
        for (int k = 0; k < 4; ++k) { s2 += sb[0][k][c]; q2 += sb[1][k][c]; }
        const float inv = 1.f / (float)(Hn * Wn);
        float mean = s2 * inv;
        float var  = fmaxf(q2 * inv - mean * mean, 0.f);
        float sc   = 1.f / (sqrtf(var) + EPS);
        scale[b * Cn + c] = sc;
        shift[b * Cn + c] = -mean * sc;
    }
}

// ---------------- K3: norm + depthwise 3x3 + pointwise + bias -> t_pad bf16 ----------------
// grid: B*HPAD*4 (4 w-quads of 16 output cols each)
__global__ __launch_bounds__(256) void k3_dwconv(const float* __restrict__ x,
                                                 const float* __restrict__ w_sp,
                                                 const float* __restrict__ w_pw,
                                                 const float* __restrict__ bias,
                                                 const float* __restrict__ scale,
                                                 const float* __restrict__ shift,
                                                 __hip_bfloat16* __restrict__ tpad) {
    const int bq = blockIdx.x;
    const int wq = bq & 3;
    const int bh = bq >> 2;
    const int b  = bh / HPAD;
    const int hp = bh - b * HPAD;       // 0..65
    const int c  = threadIdx.x;
    __hip_bfloat16* orow = tpad + ((size_t)(b * HPAD + hp)) * WPAD * Cn + c;
    const __hip_bfloat16 z = __float2bfloat16(0.f);

    if (hp == 0 || hp == HPAD - 1) {
        int wlo = wq * 17, whi = wlo + 17 < WPAD ? wlo + 17 : WPAD;
        for (int wp = wlo; wp < whi; ++wp) orow[(size_t)wp * Cn] = z;
        return;
    }
    const int h = hp - 1;
    const float sc = scale[b * Cn + c];
    const float sh = shift[b * Cn + c];
    float w9[9];
#pragma unroll
    for (int k = 0; k < 9; ++k) w9[k] = w_sp[(b * 9 + k) * Cn + c];
    const float pw = w_pw[b * Cn + c];
    const float bv = bias[b * Cn + c];
    const float* xb = x + (size_t)b * Hn * Wn * Cn + c;

    bool rv[3];
#pragma unroll
    for (int r = 0; r < 3; ++r) { int rr = h - 1 + r; rv[r] = (rr >= 0 && rr < Hn); }

    if (wq == 0) orow[0] = z;
    if (wq == 3) orow[(size_t)(WPAD - 1) * Cn] = z;

    const int w0 = wq * 16;
    float win[3][3];
#pragma unroll
    for (int r = 0; r < 3; ++r) {
        win[r][0] = (rv[r] && w0 > 0)
                    ? (xb[((size_t)(h - 1 + r) * Wn + (w0 - 1)) * Cn] * sc + sh) : 0.f;
        win[r][1] = rv[r] ? (xb[((size_t)(h - 1 + r) * Wn + w0) * Cn] * sc + sh) : 0.f;
    }
    for (int i = 0; i < 16; ++i) {
        const int w = w0 + i;
#pragma unroll
        for (int r = 0; r < 3; ++r)
            win[r][2] = (rv[r] && (w + 1) < Wn)
                        ? (xb[((size_t)(h - 1 + r) * Wn + (w + 1)) * Cn] * sc + sh) : 0.f;
        float y = 0.f;
#pragma unroll
        for (int r = 0; r < 3; ++r)
#pragma unroll
            for (int qq = 0; qq < 3; ++qq)
                y += win[r][qq] * w9[r * 3 + qq];
        orow[(size_t)(w + 1) * Cn] = __float2bfloat16(y * pw + bv);
#pragma unroll
        for (int r = 0; r < 3; ++r) { win[r][0] = win[r][1]; win[r][1] = win[r][2]; }
    }
}

// ---------------- K4: implicit-GEMM, 256x256, BK=64, DEEP 4-PHASE (corrected ledger) ------
// 512 thr = 8 waves (2m x 4n), per-wave 128x64. NT=36 K-tiles of 64. LDS: 2 buffers x
// 64KB = {A: 2 slabs (k0-31,k32-63) x 128 lines x 128B ; B: same}. Conflict-free layout
// (2 rows/128B line, slot^=(line&7), gload-linear wave-uniform dest + inverse-swizzled
// global source) — identical mapping to the R4-R11 proven pattern.
// ALL four half-tiles of T+1 are first-read at P1(T+1) (halves split across wave
// groups) and freed at P3/P4 of T-1 (same buffer). Corrected staging ledger:
//   P1(T): stage A0(T+1)   | read B kk0 + A kk0 m0-3 | bar|lgkm0| 16 MFMA | bar
//   P2(T): stage A1(T+1)   | read A kk0 m4-7          | ...
//   P3(T): (no stage)      | read B kk1 + A kk1 m0-3  | ...
//   P4(T): stage B0,B1(T+2)| read A kk1 m4-7          | ... | vmcnt(4) | bar
// end-P4 outstanding = [B(T+1) 4, A0(T+1) 2, A1(T+1) 2, B(T+2) 4] = 12 -> vmcnt(4)
// confirms EVERY tile-(T+1) half (min slack 2.5 phases ~2300cyc, no exposed latency);
// only B(T+2) stays in flight. B(T+2)@P4(T) overwrites cb's B, freed at end-P3(T). Tail:
// vmcnt(0) at T>=NT-2. (R12's bug: B1(T+1) staged P3(T), read P1(T+1), confirmed too late.)
constexpr int NT    = 36;               // K-tiles (9 taps x 256c / 64)
constexpr int BUFSZ = 65536;            // A 32KB + B 32KB

__global__ __launch_bounds__(512, 2) void k4_gemm(const __hip_bfloat16* __restrict__ tpad,
                                                  const __hip_bfloat16* __restrict__ wT,
                                                  const float* __restrict__ conv_b,
                                                  float* __restrict__ out) {
    __shared__ __align__(16) char smem[2 * BUFSZ];   // 128 KB

    const int tid  = threadIdx.x;
    const int lane = tid & 63;
    const int wv   = tid >> 6;          // 0..7
    const int wm   = wv >> 2;           // 0..1
    const int wn   = wv & 3;            // 0..3
    const int g    = lane >> 4, l15 = lane & 15;

    // XCD-chunked mapping (bijective: 8 x 16 x 4 = 512)
    const int bid = blockIdx.x;
    const int mt  = (bid & 7) * 16 + ((bid >> 3) & 15);   // 0..127
    const int nt  = bid >> 7;                             // 0..3
    const int pixbase = mt * 256;
    const int b       = mt >> 4;
    const int hbase   = (mt & 15) * 4;
    const int obase   = nt * 256;

    // ---- staging per-lane global offsets (inverse swizzle; lane unit = tid) ----
    // line r = tid>>3 (0..63 within half), phys slot p = tid&7, logical l = p^(r&7);
    // within-half row = 2r + (l>>2); k-octet = (l&3)*8.
    const int lg  = (tid & 7) ^ ((tid >> 3) & 7);
    const int rel = 2 * (tid >> 3) + (lg >> 2);      // 0..127 within half
    const int kb  = (lg & 3) * 8;
    int aoffh[2], boffh[2];
#pragma unroll
    for (int h = 0; h < 2; ++h) {
        int pix = h * 128 + rel;
        int hh  = hbase + (pix >> 6);
        int ww  = pix & 63;
        aoffh[h] = ((b * HPAD + hh) * WPAD + ww) * Cn + kb;
        boffh[h] = (obase + h * 128 + rel) * Cn + kb;
    }

    // stage half-tile: K-tile s, isB, h: 2 gloads (slab0, slab1); wave-uniform dest
    auto stage = [&](int s, int isB, int h) {
        const int tap = s >> 2, q = s & 3;
        const int kh  = tap / 3, kw = tap - 3 * kh;
        char* dst = smem + (s & 1) * BUFSZ + isB * 32768 + h * 8192
                  + (size_t)(wv * 64) * 16;
        const __hip_bfloat16* src =
            isB ? (wT + (size_t)tap * (OUTC * Cn) + q * 64 + boffh[h])
                : (tpad + ((kh * WPAD + kw) * Cn) + q * 64 + aoffh[h]);
        gload_lds16(src,      dst);
        gload_lds16(src + 32, dst + 16384);   // slab 1: k += 32
    };

    // ---- per-lane fragment read offsets (conflict-free; R4-R11 pattern) ----
    const int slot16 = ((((l15 & 1) << 2) | g) ^ ((l15 >> 1) & 7)) * 16;
    const int aR = (wm * 64 + (l15 >> 1)) * 128 + slot16;           // + m*1024 + kk*16384
    const int bR = 32768 + (wn * 32 + (l15 >> 1)) * 128 + slot16;   // + n*1024 + kk*16384

    f32x4 acc[8][4] = {};
    bf16x8 bfr[4], af[4];

    // one phase; endw: -1 = barrier only, 4/0 = vmcnt(N) before barrier
    auto phase = [&](char* cb, int mbase, int kk, bool readB, int endw) {
        if (readB) {
#pragma unroll
            for (int n = 0; n < 4; ++n)
                bfr[n] = *(const bf16x8*)(cb + bR + kk * 16384 + n * 1024);
        }
#pragma unroll
        for (int m = 0; m < 4; ++m)
            af[m] = *(const bf16x8*)(cb + aR + kk * 16384 + (mbase + m) * 1024);
        __builtin_amdgcn_sched_barrier(0);
        __builtin_amdgcn_s_barrier();
        asm volatile("s_waitcnt lgkmcnt(0)" ::: "memory");
        __builtin_amdgcn_sched_barrier(0);
        __builtin_amdgcn_s_setprio(1);
#pragma unroll
        for (int m = 0; m < 4; ++m)
#pragma unroll
            for (int n = 0; n < 4; ++n)
                acc[mbase + m][n] = __builtin_amdgcn_mfma_f32_16x16x32_bf16(
                    af[m], bfr[n], acc[mbase + m][n], 0, 0, 0);
        __builtin_amdgcn_s_setprio(0);
        __builtin_amdgcn_sched_barrier(0);
        if (endw == 4)      { asm volatile("s_waitcnt vmcnt(4)" ::: "memory"); }
        else if (endw == 0) { asm volatile("s_waitcnt vmcnt(0)" ::: "memory"); }
        __builtin_amdgcn_s_barrier();
        __builtin_amdgcn_sched_barrier(0);
    };

    // ---- prologue: T0 all halves (8 loads) + B0,B1(T1) (4 loads); confirm T0 ----
    stage(0, 0, 0); stage(0, 0, 1); stage(0, 1, 0); stage(0, 1, 1);
    stage(1, 1, 0); stage(1, 1, 1);
    asm volatile("s_waitcnt vmcnt(4)" ::: "memory");
    __builtin_amdgcn_s_barrier();
    __builtin_amdgcn_sched_barrier(0);

#pragma unroll 1
    for (int T = 0; T < NT; ++T) {
        char* cb = smem + (T & 1) * BUFSZ;
        const bool s1 = (T + 1 < NT);
        const bool s2 = (T + 2 < NT);

        if (s1) stage(T + 1, 0, 0);              // A0(T+1)
        phase(cb, 0, 0, true,  -1);              // P1: kk0, m0-3 (+B kk0)
        if (s1) stage(T + 1, 0, 1);              // A1(T+1)
        phase(cb, 4, 0, false, -1);              // P2: kk0, m4-7
        phase(cb, 0, 1, true,  -1);              // P3: kk1, m0-3 (+B kk1) — frees cb's B
        if (s2) { stage(T + 2, 1, 0); stage(T + 2, 1, 1); }   // B0,B1(T+2) -> cb's B
        phase(cb, 4, 1, false, s2 ? 4 : 0);      // P4: kk1, m4-7 | confirm tile T+1
    }

    // ---- epilogue: C frag col = l15, row = g*4+j ----
    float cb2[4];
#pragma unroll
    for (int n = 0; n < 4; ++n) cb2[n] = conv_b[obase + wn * 64 + n * 16 + l15];
#pragma unroll
    for (int m = 0; m < 8; ++m) {
#pragma unroll
        for (int j = 0; j < 4; ++j) {
            int r = pixbase + wm * 128 + m * 16 + g * 4 + j;
            float* orow = out + (size_t)r * OUTC + obase + wn * 64 + l15;
#pragma unroll
            for (int n = 0; n < 4; ++n)
                orow[n * 16] = acc[m][n][j] + cb2[n];
        }
    }
}

// ---------------- launch ----------------
extern "C" void kernel_launch(void* const* d_in, const int* in_sizes, int n_in,
                              void* d_out, int out_size, void* d_ws, size_t ws_size,
                              hipStream_t stream) {
    const float* x      = (const float*)d_in[0];
    const float* w_sp   = (const float*)d_in[1];
    const float* w_pw   = (const float*)d_in[2];
    const float* bias   = (const float*)d_in[3];
    const float* conv_w = (const float*)d_in[4];
    const float* conv_b = (const float*)d_in[5];
    float* out = (float*)d_out;

    char* ws = (char*)d_ws;
    __hip_bfloat16* wT    = (__hip_bfloat16*)(ws);
    float*          ps    = (float*)(ws + 4718592);
    float*          pq    = (float*)(ws + 4718592 + 524288);
    float*          scale = (float*)(ws + 5767168);
    float*          shift = (float*)(ws + 5775360);
    __hip_bfloat16* tpad  = (__hip_bfloat16*)(ws + 5783552);

    k0_transpose_w<<<dim3(9, 4, 16), 256, 0, stream>>>(conv_w, wT);
    k1_stats_partial<<<Bn * Hn, 1024, 0, stream>>>(x, ps, pq);
    k2_stats_final<<<Bn, 1024, 0, stream>>>(ps, pq, scale, shift);
    k3_dwconv<<<Bn * HPAD * 4, 256, 0, stream>>>(x, w_sp, w_pw, bias, scale, shift, tpad);
    k4_gemm<<<512, 512, 0, stream>>>(tpad, wT, conv_b, out);
}

// Round 14
// 177.562 us; speedup vs baseline: 1.0380x; 1.0380x over previous
//
#include <hip/hip_runtime.h>
#include <hip/hip_bf16.h>
#include <cstdint>
#include <cstddef>

// ---------------- problem constants ----------------
constexpr int Bn   = 8;
constexpr int Hn   = 64;
constexpr int Wn   = 64;
constexpr int Cn   = 256;
constexpr int OUTC = 1024;
constexpr int HPAD = 66;   // 64 + 2 halo
constexpr int WPAD = 66;
#define EPS 1e-5f

typedef __attribute__((ext_vector_type(4))) float f32x4;
typedef __bf16 bf16x8 __attribute__((ext_vector_type(8)));

// ---------------- helpers ----------------
__device__ __forceinline__ void gload_lds16(const void* g, void* l) {
    __builtin_amdgcn_global_load_lds(
        (__attribute__((address_space(1))) void*)g,
        (__attribute__((address_space(3))) void*)l,
        16, 0, 0);
}

// ---------------- K0: conv_w [3][3][256][1024] f32 -> wT [9][1024][256] bf16 ----------------
__global__ __launch_bounds__(256) void k0_transpose_w(const float* __restrict__ conv_w,
                                                      __hip_bfloat16* __restrict__ wT) {
    __shared__ float tile[64][65];
    const int tap = blockIdx.x;        // 0..8
    const int ct  = blockIdx.y;        // c-tile 0..3  (64 ch)
    const int ot  = blockIdx.z;        // o-tile 0..15 (64 out)
    const int t   = threadIdx.x;
    const int lo  = t & 63;
    const int cq  = t >> 6;            // 0..3

#pragma unroll
    for (int k = 0; k < 16; ++k) {
        int ci = k * 4 + cq;
        tile[lo][ci] = conv_w[((size_t)(tap * Cn + ct * 64 + ci)) * OUTC + ot * 64 + lo];
    }
    __syncthreads();
#pragma unroll
    for (int k = 0; k < 16; ++k) {
        int oo = k * 4 + cq;
        wT[((size_t)(tap * OUTC + ot * 64 + oo)) * Cn + ct * 64 + lo] =
            __float2bfloat16(tile[oo][lo]);
    }
}

// ---------------- K1: per-(b,h) sums over w (1024 thr: 4 w-slices x 256 ch) ----------------
__global__ __launch_bounds__(1024) void k1_stats_partial(const float* __restrict__ x,
                                                         float* __restrict__ ps,
                                                         float* __restrict__ pq) {
    __shared__ float sb[2][4][256];
    const int bh = blockIdx.x;          // b*64 + h
    const int tid = threadIdx.x;
    const int c = tid & 255;
    const int s = tid >> 8;             // 0..3
    const float* row = x + (size_t)bh * Wn * Cn + (size_t)s * 16 * Cn + c;
    float sm = 0.f, q = 0.f;
#pragma unroll
    for (int w = 0; w < 16; ++w) {
        float v = row[(size_t)w * Cn];
        sm += v; q += v * v;
    }
    sb[0][s][c] = sm; sb[1][s][c] = q;
    __syncthreads();
    if (s == 0) {
        float S = 0.f, Q = 0.f;
#pragma unroll
        for (int k = 0; k < 4; ++k) { S += sb[0][k][c]; Q += sb[1][k][c]; }
        ps[bh * Cn + c] = S;
        pq[bh * Cn + c] = Q;
    }
}

// ---------------- K2: reduce over h, produce scale/shift (1024 thr) ----------------
__global__ __launch_bounds__(1024) void k2_stats_final(const float* __restrict__ ps,
                                                       const float* __restrict__ pq,
                                                       float* __restrict__ scale,
                                                       float* __restrict__ shift) {
    __shared__ float sb[2][4][256];
    const int b = blockIdx.x;
    const int tid = threadIdx.x;
    const int c = tid & 255;
    const int qd = tid >> 8;            // 0..3, each sums 16 h
    float S = 0.f, Q = 0.f;
#pragma unroll 4
    for (int i = 0; i < 16; ++i) {
        int h = qd * 16 + i;
        S += ps[(b * Hn + h) * Cn + c];
        Q += pq[(b * Hn + h) * Cn + c];
    }
    sb[0][qd][c] = S; sb[1][qd][c] = Q;
    __syncthreads();
    if (qd == 0) {
        float s2 = 0.f, q2 = 0.f;
#pragma unroll
        for (int k = 0; k < 4; ++k) { s2 += sb[0][k][c]; q2 += sb[1][k][c]; }
        const float inv = 1.f / (float)(Hn * Wn);
        float mean = s2 * inv;
        float var  = fmaxf(q2 * inv - mean * mean, 0.f);
        float sc   = 1.f / (sqrtf(var) + EPS);
        scale[b * Cn + c] = sc;
        shift[b * Cn + c] = -mean * sc;
    }
}

// ---------------- K3: norm + depthwise 3x3 + pointwise + bias -> t_pad bf16 ----------------
// grid: B*HPAD*4 (4 w-quads of 16 output cols each)
__global__ __launch_bounds__(256) void k3_dwconv(const float* __restrict__ x,
                                                 const float* __restrict__ w_sp,
                                                 const float* __restrict__ w_pw,
                                                 const float* __restrict__ bias,
                                                 const float* __restrict__ scale,
                                                 const float* __restrict__ shift,
                                                 __hip_bfloat16* __restrict__ tpad) {
    const int bq = blockIdx.x;
    const int wq = bq & 3;
    const int bh = bq >> 2;
    const int b  = bh / HPAD;
    const int hp = bh - b * HPAD;       // 0..65
    const int c  = threadIdx.x;
    __hip_bfloat16* orow = tpad + ((size_t)(b * HPAD + hp)) * WPAD * Cn + c;
    const __hip_bfloat16 z = __float2bfloat16(0.f);

    if (hp == 0 || hp == HPAD - 1) {
        int wlo = wq * 17, whi = wlo + 17 < WPAD ? wlo + 17 : WPAD;
        for (int wp = wlo; wp < whi; ++wp) orow[(size_t)wp * Cn] = z;
        return;
    }
    const int h = hp - 1;
    const float sc = scale[b * Cn + c];
    const float sh = shift[b * Cn + c];
    float w9[9];
#pragma unroll
    for (int k = 0; k < 9; ++k) w9[k] = w_sp[(b * 9 + k) * Cn + c];
    const float pw = w_pw[b * Cn + c];
    const float bv = bias[b * Cn + c];
    const float* xb = x + (size_t)b * Hn * Wn * Cn + c;

    bool rv[3];
#pragma unroll
    for (int r = 0; r < 3; ++r) { int rr = h - 1 + r; rv[r] = (rr >= 0 && rr < Hn); }

    if (wq == 0) orow[0] = z;
    if (wq == 3) orow[(size_t)(WPAD - 1) * Cn] = z;

    const int w0 = wq * 16;
    float win[3][3];
#pragma unroll
    for (int r = 0; r < 3; ++r) {
        win[r][0] = (rv[r] && w0 > 0)
                    ? (xb[((size_t)(h - 1 + r) * Wn + (w0 - 1)) * Cn] * sc + sh) : 0.f;
        win[r][1] = rv[r] ? (xb[((size_t)(h - 1 + r) * Wn + w0) * Cn] * sc + sh) : 0.f;
    }
    for (int i = 0; i < 16; ++i) {
        const int w = w0 + i;
#pragma unroll
        for (int r = 0; r < 3; ++r)
            win[r][2] = (rv[r] && (w + 1) < Wn)
                        ? (xb[((size_t)(h - 1 + r) * Wn + (w + 1)) * Cn] * sc + sh) : 0.f;
        float y = 0.f;
#pragma unroll
        for (int r = 0; r < 3; ++r)
#pragma unroll
            for (int qq = 0; qq < 3; ++qq)
                y += win[r][qq] * w9[r * 3 + qq];
        orow[(size_t)(w + 1) * Cn] = __float2bfloat16(y * pw + bv);
#pragma unroll
        for (int r = 0; r < 3; ++r) { win[r][0] = win[r][1]; win[r][1] = win[r][2]; }
    }
}

// ---------------- K4: implicit-GEMM, 128x256 tile, 2 BLOCKS/CU (structural desync) --------
// 256 thr = 4 waves (2m x 2n), per-wave 64x128: 12 ds_read_b128 + 32 MFMA per K-step
// (BK=32). LDS: 3 bufs x 24KB (A 8KB + B 16KB) = 72KB -> TWO independent blocks per CU
// (144KB LDS, ~210 VGPR): uncoupled barriers => one block's read burst overlaps the
// other's MFMA burst (6 single-block schedules all pinned at serial LDS+MFMA sum;
// R7's 2-block test was poisoned by B-from-global HBM misses — here all LDS-staged).
// Proven conflict-free layout (2 rows/128B line, slot^=(line&7), gload-linear
// wave-uniform dest + inverse-swizzled global source). Stage-2-ahead, counted vmcnt(6).
constexpr int KSTEPS = 72;              // 9 taps x (256/32)
constexpr int BUFSZ  = 24576;           // A 8KB + B 16KB

__global__ __launch_bounds__(256, 2) void k4_gemm(const __hip_bfloat16* __restrict__ tpad,
                                                  const __hip_bfloat16* __restrict__ wT,
                                                  const float* __restrict__ conv_b,
                                                  float* __restrict__ out) {
    __shared__ __align__(16) char smem[3 * BUFSZ];   // 72 KB

    const int tid  = threadIdx.x;
    const int lane = tid & 63;
    const int wv   = tid >> 6;          // 0..3
    const int wm   = wv >> 1;           // 0..1
    const int wn   = wv & 1;            // 0..1
    const int g    = lane >> 4, l15 = lane & 15;

    // XCD-chunked mapping (bijective: 8 x 32 x 4 = 1024)
    const int bid = blockIdx.x;
    const int mt  = (bid & 7) * 32 + ((bid >> 3) & 31);   // 0..255
    const int nt  = bid >> 8;                             // 0..3
    const int pixbase = mt * 128;
    const int b       = mt >> 5;
    const int hbase   = (mt & 31) * 2;
    const int obase   = nt * 256;

    // ---- staging source offsets (inverse swizzle). A: 2 units/thread, B: 4 ----
    int aoff[2], boff[4];
#pragma unroll
    for (int j = 0; j < 2; ++j) {
        int u = j * 256 + tid;
        int r = u >> 3, p = u & 7;
        int l = p ^ (r & 7);
        int pix = 2 * r + (l >> 2);     // 0..127
        int hh  = hbase + (pix >> 6);
        int ww  = pix & 63;
        aoff[j] = ((b * HPAD + hh) * WPAD + ww) * Cn + (l & 3) * 8;
    }
#pragma unroll
    for (int j = 0; j < 4; ++j) {
        int u = j * 256 + tid;
        int r = u >> 3, p = u & 7;      // r 0..127
        int l = p ^ (r & 7);
        int och = 2 * r + (l >> 2);     // 0..255
        boff[j] = (obase + och) * Cn + (l & 3) * 8;
    }

    auto stageS = [&](int s) {
        const int tap = s >> 3, ks = s & 7;
        const int kh  = tap / 3, kw = tap - 3 * kh;
        const __hip_bfloat16* aS = tpad + ((kh * WPAD + kw) * Cn + ks * 32);
        const __hip_bfloat16* bS = wT + (size_t)tap * (OUTC * Cn) + ks * 32;
        char* buf = smem + (s % 3) * BUFSZ;
        gload_lds16(aS + aoff[0], buf + (size_t)(0 * 256 + wv * 64) * 16);
        gload_lds16(aS + aoff[1], buf + (size_t)(1 * 256 + wv * 64) * 16);
#pragma unroll
        for (int j = 0; j < 4; ++j)
            gload_lds16(bS + boff[j], buf + 8192 + (size_t)(j * 256 + wv * 64) * 16);
    };

    // ---- per-lane fragment read offsets (conflict-free; R4-proven pattern) ----
    const int slot16 = ((((l15 & 1) << 2) | g) ^ ((l15 >> 1) & 7)) * 16;
    const int aR = (wm * 32 + (l15 >> 1)) * 128 + slot16;          // + m*1024
    const int bR = 8192 + (wn * 64 + (l15 >> 1)) * 128 + slot16;   // + n*1024

    f32x4 acc[4][8] = {};

    // ---- prologue: stage K-steps 0,1 (12 loads); buf0 confirmed, stage(1) flies ----
    stageS(0);
    stageS(1);
    asm volatile("s_waitcnt vmcnt(6)" ::: "memory");
    __builtin_amdgcn_s_barrier();
    __builtin_amdgcn_sched_barrier(0);

#pragma unroll 1
    for (int t = 0; t < KSTEPS; ++t) {
        char* cb = smem + (t % 3) * BUFSZ;
        bf16x8 bfr[8], af[4];
#pragma unroll
        for (int n = 0; n < 8; ++n)
            bfr[n] = *(const bf16x8*)(cb + bR + n * 1024);
#pragma unroll
        for (int m = 0; m < 4; ++m)
            af[m] = *(const bf16x8*)(cb + aR + m * 1024);

        if (t + 2 < KSTEPS) stageS(t + 2);   // writes buf (t+2)%3 = (t-1)%3, freed last step

        __builtin_amdgcn_s_setprio(1);
#pragma unroll
        for (int m = 0; m < 4; ++m)
#pragma unroll
            for (int n = 0; n < 8; ++n)
                acc[m][n] = __builtin_amdgcn_mfma_f32_16x16x32_bf16(
                    af[m], bfr[n], acc[m][n], 0, 0, 0);
        __builtin_amdgcn_s_setprio(0);
        __builtin_amdgcn_sched_barrier(0);

        // step boundary: buf t+1 must be complete; stage(t+2)'s 6 loads may fly
        if (t + 1 < KSTEPS) {
            if (t + 2 < KSTEPS) { asm volatile("s_waitcnt vmcnt(6)" ::: "memory"); }
            else                { asm volatile("s_waitcnt vmcnt(0)" ::: "memory"); }
            __builtin_amdgcn_s_barrier();
            __builtin_amdgcn_sched_barrier(0);
        }
    }

    // ---- epilogue: C frag col = l15, row = g*4+j ----
    float cb2[8];
#pragma unroll
    for (int n = 0; n < 8; ++n) cb2[n] = conv_b[obase + wn * 128 + n * 16 + l15];
#pragma unroll
    for (int m = 0; m < 4; ++m) {
#pragma unroll
        for (int j = 0; j < 4; ++j) {
            int r = pixbase + wm * 64 + m * 16 + g * 4 + j;
            float* orow = out + (size_t)r * OUTC + obase + wn * 128 + l15;
#pragma unroll
            for (int n = 0; n < 8; ++n)
                orow[n * 16] = acc[m][n][j] + cb2[n];
        }
    }
}

// ---------------- launch ----------------
extern "C" void kernel_launch(void* const* d_in, const int* in_sizes, int n_in,
                              void* d_out, int out_size, void* d_ws, size_t ws_size,
                              hipStream_t stream) {
    const float* x      = (const float*)d_in[0];
    const float* w_sp   = (const float*)d_in[1];
    const float* w_pw   = (const float*)d_in[2];
    const float* bias   = (const float*)d_in[3];
    const float* conv_w = (const float*)d_in[4];
    const float* conv_b = (const float*)d_in[5];
    float* out = (float*)d_out;

    char* ws = (char*)d_ws;
    __hip_bfloat16* wT    = (__hip_bfloat16*)(ws);
    float*          ps    = (float*)(ws + 4718592);
    float*          pq    = (float*)(ws + 4718592 + 524288);
    float*          scale = (float*)(ws + 5767168);
    float*          shift = (float*)(ws + 5775360);
    __hip_bfloat16* tpad  = (__hip_bfloat16*)(ws + 5783552);

    k0_transpose_w<<<dim3(9, 4, 16), 256, 0, stream>>>(conv_w, wT);
    k1_stats_partial<<<Bn * Hn, 1024, 0, stream>>>(x, ps, pq);
    k2_stats_final<<<Bn, 1024, 0, stream>>>(ps, pq, scale, shift);
    k3_dwconv<<<Bn * HPAD * 4, 256, 0, stream>>>(x, w_sp, w_pw, bias, scale, shift, tpad);
    k4_gemm<<<1024, 256, 0, stream>>>(tpad, wT, conv_b, out);
}